// Round 2
// baseline (10052.127 us; speedup 1.0000x reference)
//
#include <hip/hip_runtime.h>
#include <stdint.h>

typedef __attribute__((ext_vector_type(8))) short short8;
typedef __attribute__((ext_vector_type(4))) float f32x4;

#define DEV static __device__ __forceinline__

DEV unsigned short f2bf(float f) {
  union { float f; uint32_t u; } v; v.f = f;
  uint32_t r = (v.u + 0x7fffu + ((v.u >> 16) & 1u)) >> 16;
  return (unsigned short)r;
}
DEV float bf2f(unsigned short h) {
  union { uint32_t u; float f; } v; v.u = ((uint32_t)h) << 16;
  return v.f;
}
DEV float fsigmoid(float x) { return 1.f / (1.f + __expf(-x)); }
DEV float ftanh(float x) {
  float e = __expf(2.f * x);
  return 1.f - 2.f / (e + 1.f);
}
DEV short8 pack_bf16x8(f32x4 lo, f32x4 hi) {
  short8 a;
#pragma unroll
  for (int j = 0; j < 4; ++j) { a[j] = (short)f2bf(lo[j]); a[4 + j] = (short)f2bf(hi[j]); }
  return a;
}

// ---------------- output offsets (floats) ----------------
// output_ (64,100,512) | hT (64,512) | cT | haT | attns (100,64,1024) | paT (64,1024) | p_gen (64,100) | past_dehy (64,1,512) | loss (1)
static const size_t O_HT    = 3276800;
static const size_t O_CT    = 3309568;
static const size_t O_HAT   = 3342336;
static const size_t O_ATTNS = 3375104;
static const size_t O_PAT   = 9928704;
static const size_t O_PGEN  = 9994240;
static const size_t O_PDEHY = 10000640;
static const size_t O_LOSS  = 10033408;

// ---------------- setup kernels ----------------
__global__ __launch_bounds__(256) void k_conv_bf16(const float* __restrict__ in,
                                                   unsigned short* __restrict__ out) {
  size_t i = (size_t)blockIdx.x * blockDim.x + threadIdx.x;  // one f32x4 per thread
  f32x4 v = ((const f32x4*)in)[i];
  uint32_t lo = (uint32_t)f2bf(v[0]) | ((uint32_t)f2bf(v[1]) << 16);
  uint32_t hi = (uint32_t)f2bf(v[2]) | ((uint32_t)f2bf(v[3]) << 16);
  ((uint2*)out)[i] = make_uint2(lo, hi);
}

__global__ __launch_bounds__(256) void k_build_wcomb(const float* __restrict__ wih,
                                                     const float* __restrict__ whh,
                                                     unsigned short* __restrict__ wc) {
  int i = blockIdx.x * blockDim.x + threadIdx.x;  // 655360 threads, 4 elems each
  int base = i * 4;
  int n = base / 1280, k = base - n * 1280;
  const float* src = (k < 768) ? (wih + (size_t)n * 768 + k) : (whh + (size_t)n * 512 + (k - 768));
  f32x4 v = *(const f32x4*)src;
  uint32_t lo = (uint32_t)f2bf(v[0]) | ((uint32_t)f2bf(v[1]) << 16);
  uint32_t hi = (uint32_t)f2bf(v[2]) | ((uint32_t)f2bf(v[3]) << 16);
  ((uint2*)wc)[i] = make_uint2(lo, hi);
}

__global__ __launch_bounds__(256) void k_bias(const float* __restrict__ a,
                                              const float* __restrict__ b,
                                              float* __restrict__ o) {
  int i = blockIdx.x * blockDim.x + threadIdx.x;
  o[i] = a[i] + b[i];
}

// ---------------- MFMA GEMM: C = A(MxK,bf16) * B^T(NxK,bf16) + bias ----------------
template <int MT, int NT, int KK, int OUTBF>
__global__ __launch_bounds__(256) void k_gemm_bt(const unsigned short* __restrict__ A,
                                                 const unsigned short* __restrict__ Bm,
                                                 const float* __restrict__ bias,
                                                 void* __restrict__ C, int ldc) {
  int wid = (int)((blockIdx.x * blockDim.x + threadIdx.x) >> 6);
  int lane = threadIdx.x & 63;
  int tm = wid % MT, tn = wid / MT;
  int r = lane & 15, q = lane >> 4;
  const short8* Ap = (const short8*)(A + (size_t)(tm * 16 + r) * KK + q * 8);
  const short8* Bp = (const short8*)(Bm + (size_t)(tn * 16 + r) * KK + q * 8);
  f32x4 acc = {0.f, 0.f, 0.f, 0.f};
#pragma unroll 4
  for (int kk = 0; kk < KK / 32; ++kk) {
    acc = __builtin_amdgcn_mfma_f32_16x16x32_bf16(Ap[kk * 4], Bp[kk * 4], acc, 0, 0, 0);
  }
  int col = tn * 16 + r;
  float bv = bias ? bias[col] : 0.f;
#pragma unroll
  for (int rg = 0; rg < 4; ++rg) {
    int row = tm * 16 + q * 4 + rg;
    float v = acc[rg] + bv;
    if (OUTBF) ((unsigned short*)C)[(size_t)row * ldc + col] = f2bf(v);
    else       ((float*)C)[(size_t)row * ldc + col] = v;
  }
}

// ---------------- K1: fused pack + gates GEMM + LSTM ----------------
// grid 32 blocks (n-slices of 16 cols), 256 threads = 4 waves (m-tiles of 16 rows).
// Each wave computes the 4 gate quadrants for its (16 rows x 16 cols) tile, then
// applies the LSTM pointwise update in the epilogue (i,f,g,o meet in registers).
__global__ __launch_bounds__(256) void k_gates_lstm(
    const float* __restrict__ input_, const float* __restrict__ ha,
    const unsigned short* __restrict__ hbp,   // h_{t-1} bf16
    const unsigned short* __restrict__ wcomb, // (2048,1280) bf16
    const float* __restrict__ biasc,          // (2048) = b_ih+b_hh
    float* __restrict__ h, float* __restrict__ c,
    unsigned short* __restrict__ hbn,         // h_t bf16
    int t) {
  int wave = threadIdx.x >> 6, lane = threadIdx.x & 63;
  int r = lane & 15, q = lane >> 4;
  int ns = blockIdx.x;
  int arow = wave * 16 + r;   // batch row for A fragment
  int bcol = ns * 16 + r;     // output col (within each gate quadrant)
  const unsigned short* B0 = wcomb + (size_t)(bcol) * 1280;
  const unsigned short* B1 = wcomb + (size_t)(512 + bcol) * 1280;
  const unsigned short* B2 = wcomb + (size_t)(1024 + bcol) * 1280;
  const unsigned short* B3 = wcomb + (size_t)(1536 + bcol) * 1280;
  f32x4 acc0 = {0.f,0.f,0.f,0.f}, acc1 = acc0, acc2 = acc0, acc3 = acc0;
#pragma unroll 4
  for (int kk = 0; kk < 40; ++kk) {
    int k0 = kk * 32 + q * 8;
    short8 a;
    if (k0 < 256) {
      const f32x4* p = (const f32x4*)(input_ + ((size_t)arow * 100 + t) * 256 + k0);
      a = pack_bf16x8(p[0], p[1]);
    } else if (k0 < 768) {
      const f32x4* p = (const f32x4*)(ha + (size_t)arow * 512 + (k0 - 256));
      a = pack_bf16x8(p[0], p[1]);
    } else {
      a = *(const short8*)(hbp + (size_t)arow * 512 + (k0 - 768));
    }
    acc0 = __builtin_amdgcn_mfma_f32_16x16x32_bf16(a, *(const short8*)(B0 + k0), acc0, 0, 0, 0);
    acc1 = __builtin_amdgcn_mfma_f32_16x16x32_bf16(a, *(const short8*)(B1 + k0), acc1, 0, 0, 0);
    acc2 = __builtin_amdgcn_mfma_f32_16x16x32_bf16(a, *(const short8*)(B2 + k0), acc2, 0, 0, 0);
    acc3 = __builtin_amdgcn_mfma_f32_16x16x32_bf16(a, *(const short8*)(B3 + k0), acc3, 0, 0, 0);
  }
  int col = ns * 16 + r;
  float bi = biasc[col], bf = biasc[512 + col], bg = biasc[1024 + col], bo = biasc[1536 + col];
#pragma unroll
  for (int rg = 0; rg < 4; ++rg) {
    int b = wave * 16 + q * 4 + rg;
    size_t idx = (size_t)b * 512 + col;
    float iv = fsigmoid(acc0[rg] + bi);
    float fv = fsigmoid(acc1[rg] + bf);
    float gv = ftanh(acc2[rg] + bg);
    float ov = fsigmoid(acc3[rg] + bo);
    float cn = fv * c[idx] + iv * gv;
    float hn = ov * ftanh(cn);
    c[idx] = cn; h[idx] = hn; hbn[idx] = f2bf(hn);
  }
}

// ---------------- K3: attention scores ----------------
__global__ __launch_bounds__(256) void k_attn_ee(const unsigned short* __restrict__ ep,
                                                 const float* __restrict__ de,
                                                 const float* __restrict__ cv,
                                                 const float* __restrict__ wwarp,
                                                 const float* __restrict__ pa,
                                                 float* __restrict__ ee) {
  int wid = (int)((blockIdx.x * blockDim.x + threadIdx.x) >> 6);  // one wave per (b,s)
  int lane = threadIdx.x & 63;
  int b = wid >> 10, s = wid & 1023;
  float pav = pa[(size_t)b * 1024 + s];
  short8 v = *(const short8*)(ep + ((size_t)b * 1024 + s) * 512 + lane * 8);
  const f32x4* dp = (const f32x4*)(de + b * 512 + lane * 8);
  f32x4 d0 = dp[0], d1 = dp[1];
  const f32x4* cp = (const f32x4*)(cv + lane * 8);
  f32x4 c0 = cp[0], c1 = cp[1];
  const f32x4* wp = (const f32x4*)(wwarp + lane * 8);
  f32x4 w0 = wp[0], w1 = wp[1];
  float acc = 0.f;
#pragma unroll
  for (int j = 0; j < 4; ++j) {
    float x0 = bf2f((unsigned short)v[j]) + d0[j] + pav * c0[j];
    acc += ftanh(x0) * w0[j];
    float x1 = bf2f((unsigned short)v[4 + j]) + d1[j] + pav * c1[j];
    acc += ftanh(x1) * w1[j];
  }
#pragma unroll
  for (int off = 32; off > 0; off >>= 1) acc += __shfl_xor(acc, off, 64);
  if (lane == 0) ee[(size_t)b * 1024 + s] = acc;
}

// ---------------- K4: fused softmax + pa update + c_enc ----------------
// one block per batch, 1024 threads (16 waves).
__global__ __launch_bounds__(1024) void k_softmax_cenc(
    const float* __restrict__ ee, const unsigned short* __restrict__ encb,
    float* __restrict__ attns_out, float* __restrict__ pa, float* __restrict__ cenc) {
  int b = blockIdx.x, tid = threadIdx.x;
  int wv = tid >> 6, lane = tid & 63;
  __shared__ float red[16];
  __shared__ float attn_s[1024];
  __shared__ float part[4][512];
  float v = ee[(size_t)b * 1024 + tid];
  float m = v;
#pragma unroll
  for (int off = 32; off > 0; off >>= 1) m = fmaxf(m, __shfl_xor(m, off, 64));
  if (lane == 0) red[wv] = m;
  __syncthreads();
  m = red[0];
#pragma unroll
  for (int i = 1; i < 16; ++i) m = fmaxf(m, red[i]);
  float e = __expf(v - m);
  float s = e;
#pragma unroll
  for (int off = 32; off > 0; off >>= 1) s += __shfl_xor(s, off, 64);
  __syncthreads();
  if (lane == 0) red[wv] = s;
  __syncthreads();
  s = 0.f;
#pragma unroll
  for (int i = 0; i < 16; ++i) s += red[i];
  float a = e * (1.f / s);
  attn_s[tid] = a;
  attns_out[(size_t)b * 1024 + tid] = a;
  pa[(size_t)b * 1024 + tid] += a;
  __syncthreads();
  // c_enc: thread owns 2 enc dims, quarter of the s range; 16 waves in flight.
  int quarter = tid >> 8, cp = tid & 255;
  const uint32_t* ep = (const uint32_t*)(encb + ((size_t)b * 1024 + quarter * 256) * 512) + cp;
  const float* at = attn_s + quarter * 256;
  float a0 = 0.f, a1 = 0.f;
#pragma unroll 8
  for (int si = 0; si < 256; ++si) {
    float w = at[si];
    uint32_t pk = ep[(size_t)si * 256];
    a0 += w * bf2f((unsigned short)(pk & 0xffffu));
    a1 += w * bf2f((unsigned short)(pk >> 16));
  }
  part[quarter][cp * 2] = a0;
  part[quarter][cp * 2 + 1] = a1;
  __syncthreads();
  if (tid < 512)
    cenc[(size_t)b * 512 + tid] = part[0][tid] + part[1][tid] + part[2][tid] + part[3][tid];
}

// ---------------- K5: fused ha-GEMM + output writes + p_gen ----------------
// blocks 0..31: ha = [c_enc | h] @ w_ao^T + b_ao (M=64,N=512,K=1024), epilogue
// writes ha buffer + output_ (+haT at t=99). blocks 32..95: p_gen per batch
// (+hT/cT at t=99).
__global__ __launch_bounds__(256) void k_ha_pout(
    const float* __restrict__ cenc, const unsigned short* __restrict__ hb,
    const unsigned short* __restrict__ Bm, const float* __restrict__ bias,
    float* __restrict__ ha,
    const float* __restrict__ input_, const float* __restrict__ h,
    const float* __restrict__ c,
    const float* __restrict__ wpt, const float* __restrict__ bpt,
    float* __restrict__ dout, int t) {
  if (blockIdx.x < 32) {
    int wid = (int)(blockIdx.x * 4 + (threadIdx.x >> 6));
    int lane = threadIdx.x & 63;
    int tm = wid & 3, tn = wid >> 2;
    int r = lane & 15, q = lane >> 4;
    int arow = tm * 16 + r;
    f32x4 acc = {0.f, 0.f, 0.f, 0.f};
#pragma unroll
    for (int kk = 0; kk < 32; ++kk) {
      int k0 = kk * 32 + q * 8;
      short8 a;
      if (k0 < 512) {
        const f32x4* p = (const f32x4*)(cenc + (size_t)arow * 512 + k0);
        a = pack_bf16x8(p[0], p[1]);
      } else {
        a = *(const short8*)(hb + (size_t)arow * 512 + (k0 - 512));
      }
      short8 bfr = *(const short8*)(Bm + (size_t)(tn * 16 + r) * 1024 + k0);
      acc = __builtin_amdgcn_mfma_f32_16x16x32_bf16(a, bfr, acc, 0, 0, 0);
    }
    int col = tn * 16 + r;
    float bv = bias[col];
#pragma unroll
    for (int rg = 0; rg < 4; ++rg) {
      int row = tm * 16 + q * 4 + rg;
      float v = acc[rg] + bv;
      ha[(size_t)row * 512 + col] = v;
      dout[((size_t)row * 100 + t) * 512 + col] = v;
      if (t == 99) dout[O_HAT + (size_t)row * 512 + col] = v;
    }
  } else {
    int b = blockIdx.x - 32, tid = threadIdx.x;
    float acc = 0.f;
#pragma unroll
    for (int k = tid; k < 1280; k += 256) {
      float x;
      if (k < 256)      x = input_[((size_t)b * 100 + t) * 256 + k];
      else if (k < 768) x = h[(size_t)b * 512 + (k - 256)];
      else              x = cenc[(size_t)b * 512 + (k - 768)];
      acc += x * wpt[k];
    }
    int wv = tid >> 6, lane = tid & 63;
    __shared__ float red[4];
#pragma unroll
    for (int off = 32; off > 0; off >>= 1) acc += __shfl_xor(acc, off, 64);
    if (lane == 0) red[wv] = acc;
    __syncthreads();
    if (tid == 0) {
      float p = fsigmoid(red[0] + red[1] + red[2] + red[3] + bpt[0]);
      dout[O_PGEN + (size_t)b * 100 + t] = p;
    }
    if (t == 99) {
      dout[O_HT + (size_t)b * 512 + tid]       = h[(size_t)b * 512 + tid];
      dout[O_HT + (size_t)b * 512 + 256 + tid] = h[(size_t)b * 512 + 256 + tid];
      dout[O_CT + (size_t)b * 512 + tid]       = c[(size_t)b * 512 + tid];
      dout[O_CT + (size_t)b * 512 + 256 + tid] = c[(size_t)b * 512 + 256 + tid];
    }
  }
}

extern "C" void kernel_launch(void* const* d_in, const int* in_sizes, int n_in,
                              void* d_out, int out_size, void* d_ws, size_t ws_size,
                              hipStream_t stream) {
  const float* input_    = (const float*)d_in[1];
  const float* h0        = (const float*)d_in[2];
  const float* c0        = (const float*)d_in[3];
  const float* h_attn    = (const float*)d_in[4];
  const float* encoder_hy= (const float*)d_in[5];
  const float* past_attn = (const float*)d_in[6];
  const float* past_dehy = (const float*)d_in[7];
  const float* w_ih      = (const float*)d_in[8];
  const float* b_ih      = (const float*)d_in[9];
  const float* w_hh      = (const float*)d_in[10];
  const float* b_hh      = (const float*)d_in[11];
  const float* w_en      = (const float*)d_in[12];
  const float* b_en      = (const float*)d_in[13];
  const float* w_de      = (const float*)d_in[14];
  const float* w_cv      = (const float*)d_in[15];
  const float* w_warp    = (const float*)d_in[16];
  const float* w_ao      = (const float*)d_in[17];
  const float* b_ao      = (const float*)d_in[18];
  const float* w_pt      = (const float*)d_in[19];
  const float* b_pt      = (const float*)d_in[20];

  char* ws = (char*)d_ws;
  unsigned short* encb  = (unsigned short*)(ws + 0);           //  67,108,864 B
  unsigned short* epb   = (unsigned short*)(ws + 67108864);    //  67,108,864 B
  unsigned short* wcomb = (unsigned short*)(ws + 134217728);   //   5,242,880 B
  unsigned short* wenb  = (unsigned short*)(ws + 139460608);   //     524,288 B
  unsigned short* wdeb  = (unsigned short*)(ws + 139984896);   //     524,288 B
  unsigned short* waob  = (unsigned short*)(ws + 140509184);   //   1,048,576 B
  float* biasc          = (float*)(ws + 141557760);            //       8,192 B
  float* h              = (float*)(ws + 141565952);            //     131,072 B
  float* c              = (float*)(ws + 141697024);            //     131,072 B
  float* ha             = (float*)(ws + 141828096);            //     131,072 B
  unsigned short* hbA   = (unsigned short*)(ws + 141959168);   //      65,536 B
  unsigned short* hbB   = (unsigned short*)(ws + 142024704);   //      65,536 B
  float* de             = (float*)(ws + 142090240);            //     131,072 B
  float* ee             = (float*)(ws + 142221312);            //     262,144 B
  float* cenc           = (float*)(ws + 142483456);            //     131,072 B

  float* out = (float*)d_out;
  float* pa = out + O_PAT;  // pa state lives in the paT output slot

  // ---- init state ----
  hipMemcpyAsync(h,  h0,     32768 * 4, hipMemcpyDeviceToDevice, stream);
  hipMemcpyAsync(c,  c0,     32768 * 4, hipMemcpyDeviceToDevice, stream);
  hipMemcpyAsync(ha, h_attn, 32768 * 4, hipMemcpyDeviceToDevice, stream);
  hipMemcpyAsync(pa, past_attn, 65536 * 4, hipMemcpyDeviceToDevice, stream);
  hipMemcpyAsync(out + O_PDEHY, past_dehy, 32768 * 4, hipMemcpyDeviceToDevice, stream);
  hipMemsetAsync(out + O_LOSS, 0, 4, stream);

  // ---- one-time conversions + enc_proj ----
  k_conv_bf16<<<32768, 256, 0, stream>>>(encoder_hy, encb);
  k_conv_bf16<<<256, 256, 0, stream>>>(w_en, wenb);
  k_conv_bf16<<<256, 256, 0, stream>>>(w_de, wdeb);
  k_conv_bf16<<<512, 256, 0, stream>>>(w_ao, waob);
  k_conv_bf16<<<32, 256, 0, stream>>>(h0, hbA);
  k_build_wcomb<<<2560, 256, 0, stream>>>(w_ih, w_hh, wcomb);
  k_bias<<<8, 256, 0, stream>>>(b_ih, b_hh, biasc);

  // enc_proj (65536x512, K=512) -> bf16
  k_gemm_bt<4096, 32, 512, 1><<<32768, 256, 0, stream>>>(encb, wenb, b_en, epb, 512);

  for (int t = 0; t < 100; ++t) {
    unsigned short* hbp = (t & 1) ? hbB : hbA;
    unsigned short* hbn = (t & 1) ? hbA : hbB;
    k_gates_lstm<<<32, 256, 0, stream>>>(input_, ha, hbp, wcomb, biasc, h, c, hbn, t);
    k_gemm_bt<4, 32, 512, 0><<<32, 256, 0, stream>>>(hbn, wdeb, nullptr, de, 512);
    k_attn_ee<<<16384, 256, 0, stream>>>(epb, de, w_cv, w_warp, pa, ee);
    k_softmax_cenc<<<64, 1024, 0, stream>>>(ee, encb, out + O_ATTNS + (size_t)t * 65536, pa, cenc);
    k_ha_pout<<<96, 256, 0, stream>>>(cenc, hbn, waob, b_ao, ha,
                                      input_, h, c, w_pt, b_pt, out, t);
  }
}

// Round 3
// 9828.204 us; speedup vs baseline: 1.0228x; 1.0228x over previous
//
#include <hip/hip_runtime.h>
#include <stdint.h>

typedef __attribute__((ext_vector_type(8))) short short8;
typedef __attribute__((ext_vector_type(4))) float f32x4;

#define DEV static __device__ __forceinline__

DEV unsigned short f2bf(float f) {
  union { float f; uint32_t u; } v; v.f = f;
  uint32_t r = (v.u + 0x7fffu + ((v.u >> 16) & 1u)) >> 16;
  return (unsigned short)r;
}
DEV float bf2f(unsigned short h) {
  union { uint32_t u; float f; } v; v.u = ((uint32_t)h) << 16;
  return v.f;
}
DEV float fsigmoid(float x) { return 1.f / (1.f + __expf(-x)); }
DEV float ftanh(float x) {
  float e = __expf(2.f * x);
  return 1.f - 2.f / (e + 1.f);
}
DEV short8 pack_bf16x8(f32x4 lo, f32x4 hi) {
  short8 a;
#pragma unroll
  for (int j = 0; j < 4; ++j) { a[j] = (short)f2bf(lo[j]); a[4 + j] = (short)f2bf(hi[j]); }
  return a;
}

// ---------------- output offsets (floats) ----------------
static const size_t O_HT    = 3276800;
static const size_t O_CT    = 3309568;
static const size_t O_HAT   = 3342336;
static const size_t O_ATTNS = 3375104;
static const size_t O_PAT   = 9928704;
static const size_t O_PGEN  = 9994240;
static const size_t O_PDEHY = 10000640;
static const size_t O_LOSS  = 10033408;

// ---------------- setup kernels ----------------
__global__ __launch_bounds__(256) void k_conv_bf16(const float* __restrict__ in,
                                                   unsigned short* __restrict__ out) {
  size_t i = (size_t)blockIdx.x * blockDim.x + threadIdx.x;
  f32x4 v = ((const f32x4*)in)[i];
  uint32_t lo = (uint32_t)f2bf(v[0]) | ((uint32_t)f2bf(v[1]) << 16);
  uint32_t hi = (uint32_t)f2bf(v[2]) | ((uint32_t)f2bf(v[3]) << 16);
  ((uint2*)out)[i] = make_uint2(lo, hi);
}

__global__ __launch_bounds__(256) void k_build_wcomb(const float* __restrict__ wih,
                                                     const float* __restrict__ whh,
                                                     unsigned short* __restrict__ wc) {
  int i = blockIdx.x * blockDim.x + threadIdx.x;
  int base = i * 4;
  int n = base / 1280, k = base - n * 1280;
  const float* src = (k < 768) ? (wih + (size_t)n * 768 + k) : (whh + (size_t)n * 512 + (k - 768));
  f32x4 v = *(const f32x4*)src;
  uint32_t lo = (uint32_t)f2bf(v[0]) | ((uint32_t)f2bf(v[1]) << 16);
  uint32_t hi = (uint32_t)f2bf(v[2]) | ((uint32_t)f2bf(v[3]) << 16);
  ((uint2*)wc)[i] = make_uint2(lo, hi);
}

__global__ __launch_bounds__(256) void k_bias(const float* __restrict__ a,
                                              const float* __restrict__ b,
                                              float* __restrict__ o) {
  int i = blockIdx.x * blockDim.x + threadIdx.x;
  o[i] = a[i] + b[i];
}

// ---------------- MFMA GEMM: C = A(MxK,bf16) * B^T(NxK,bf16) + bias ----------------
template <int MT, int NT, int KK, int OUTBF>
__global__ __launch_bounds__(256) void k_gemm_bt(const unsigned short* __restrict__ A,
                                                 const unsigned short* __restrict__ Bm,
                                                 const float* __restrict__ bias,
                                                 void* __restrict__ C, int ldc) {
  int wid = (int)((blockIdx.x * blockDim.x + threadIdx.x) >> 6);
  int lane = threadIdx.x & 63;
  int tm = wid % MT, tn = wid / MT;
  int r = lane & 15, q = lane >> 4;
  const short8* Ap = (const short8*)(A + (size_t)(tm * 16 + r) * KK + q * 8);
  const short8* Bp = (const short8*)(Bm + (size_t)(tn * 16 + r) * KK + q * 8);
  f32x4 acc = {0.f, 0.f, 0.f, 0.f};
#pragma unroll 4
  for (int kk = 0; kk < KK / 32; ++kk) {
    acc = __builtin_amdgcn_mfma_f32_16x16x32_bf16(Ap[kk * 4], Bp[kk * 4], acc, 0, 0, 0);
  }
  int col = tn * 16 + r;
  float bv = bias ? bias[col] : 0.f;
#pragma unroll
  for (int rg = 0; rg < 4; ++rg) {
    int row = tm * 16 + q * 4 + rg;
    float v = acc[rg] + bv;
    if (OUTBF) ((unsigned short*)C)[(size_t)row * ldc + col] = f2bf(v);
    else       ((float*)C)[(size_t)row * ldc + col] = v;
  }
}

// ---------------- K1: fused pack + gates GEMM + LSTM (+ cenc zeroing) ----------------
__global__ __launch_bounds__(256) void k_gates_lstm(
    const float* __restrict__ input_, const float* __restrict__ ha,
    const unsigned short* __restrict__ hbp,   // h_{t-1} bf16
    const unsigned short* __restrict__ wcomb, // (2048,1280) bf16
    const float* __restrict__ biasc,          // (2048) = b_ih+b_hh
    float* __restrict__ h, float* __restrict__ c,
    unsigned short* __restrict__ hbn,         // h_t bf16
    float* __restrict__ cenc,                 // zeroed here for this step
    int t) {
  // zero cenc (consumed by previous step's k_ha_pout; rebuilt later this step)
  {
    f32x4 z = {0.f, 0.f, 0.f, 0.f};
    ((f32x4*)cenc)[blockIdx.x * 256 + threadIdx.x] = z;  // 32*256*4 = 32768 floats
  }
  int wave = threadIdx.x >> 6, lane = threadIdx.x & 63;
  int r = lane & 15, q = lane >> 4;
  int ns = blockIdx.x;
  int arow = wave * 16 + r;
  int bcol = ns * 16 + r;
  const unsigned short* B0 = wcomb + (size_t)(bcol) * 1280;
  const unsigned short* B1 = wcomb + (size_t)(512 + bcol) * 1280;
  const unsigned short* B2 = wcomb + (size_t)(1024 + bcol) * 1280;
  const unsigned short* B3 = wcomb + (size_t)(1536 + bcol) * 1280;
  f32x4 acc0 = {0.f,0.f,0.f,0.f}, acc1 = acc0, acc2 = acc0, acc3 = acc0;
#pragma unroll 4
  for (int kk = 0; kk < 40; ++kk) {
    int k0 = kk * 32 + q * 8;
    short8 a;
    if (k0 < 256) {
      const f32x4* p = (const f32x4*)(input_ + ((size_t)arow * 100 + t) * 256 + k0);
      a = pack_bf16x8(p[0], p[1]);
    } else if (k0 < 768) {
      const f32x4* p = (const f32x4*)(ha + (size_t)arow * 512 + (k0 - 256));
      a = pack_bf16x8(p[0], p[1]);
    } else {
      a = *(const short8*)(hbp + (size_t)arow * 512 + (k0 - 768));
    }
    acc0 = __builtin_amdgcn_mfma_f32_16x16x32_bf16(a, *(const short8*)(B0 + k0), acc0, 0, 0, 0);
    acc1 = __builtin_amdgcn_mfma_f32_16x16x32_bf16(a, *(const short8*)(B1 + k0), acc1, 0, 0, 0);
    acc2 = __builtin_amdgcn_mfma_f32_16x16x32_bf16(a, *(const short8*)(B2 + k0), acc2, 0, 0, 0);
    acc3 = __builtin_amdgcn_mfma_f32_16x16x32_bf16(a, *(const short8*)(B3 + k0), acc3, 0, 0, 0);
  }
  int col = ns * 16 + r;
  float bi = biasc[col], bf = biasc[512 + col], bg = biasc[1024 + col], bo = biasc[1536 + col];
#pragma unroll
  for (int rg = 0; rg < 4; ++rg) {
    int b = wave * 16 + q * 4 + rg;
    size_t idx = (size_t)b * 512 + col;
    float iv = fsigmoid(acc0[rg] + bi);
    float fv = fsigmoid(acc1[rg] + bf);
    float gv = ftanh(acc2[rg] + bg);
    float ov = fsigmoid(acc3[rg] + bo);
    float cn = fv * c[idx] + iv * gv;
    float hn = ov * ftanh(cn);
    c[idx] = cn; h[idx] = hn; hbn[idx] = f2bf(hn);
  }
}

// ---------------- K3: attention scores + per-block softmax partials ----------------
// 16384 blocks; block = 4 consecutive s of one batch; writes ee + (m,l) partial.
__global__ __launch_bounds__(256) void k_attn_ee(const unsigned short* __restrict__ ep,
                                                 const float* __restrict__ de,
                                                 const float* __restrict__ cv,
                                                 const float* __restrict__ wwarp,
                                                 const float* __restrict__ pa,
                                                 float* __restrict__ ee,
                                                 float2* __restrict__ partials) {
  int wave = threadIdx.x >> 6;
  int wid = (int)(blockIdx.x * 4 + wave);
  int lane = threadIdx.x & 63;
  int b = wid >> 10, s = wid & 1023;
  float pav = pa[(size_t)b * 1024 + s];
  short8 v = *(const short8*)(ep + ((size_t)b * 1024 + s) * 512 + lane * 8);
  const f32x4* dp = (const f32x4*)(de + b * 512 + lane * 8);
  f32x4 d0 = dp[0], d1 = dp[1];
  const f32x4* cp = (const f32x4*)(cv + lane * 8);
  f32x4 c0 = cp[0], c1 = cp[1];
  const f32x4* wp = (const f32x4*)(wwarp + lane * 8);
  f32x4 w0 = wp[0], w1 = wp[1];
  float acc = 0.f;
#pragma unroll
  for (int j = 0; j < 4; ++j) {
    float x0 = bf2f((unsigned short)v[j]) + d0[j] + pav * c0[j];
    acc += ftanh(x0) * w0[j];
    float x1 = bf2f((unsigned short)v[4 + j]) + d1[j] + pav * c1[j];
    acc += ftanh(x1) * w1[j];
  }
#pragma unroll
  for (int off = 32; off > 0; off >>= 1) acc += __shfl_xor(acc, off, 64);
  __shared__ float ees[4];
  if (lane == 0) {
    ee[(size_t)b * 1024 + s] = acc;
    ees[wave] = acc;
  }
  __syncthreads();
  if (threadIdx.x == 0) {
    float m = fmaxf(fmaxf(ees[0], ees[1]), fmaxf(ees[2], ees[3]));
    float l = __expf(ees[0] - m) + __expf(ees[1] - m) + __expf(ees[2] - m) + __expf(ees[3] - m);
    partials[blockIdx.x] = make_float2(m, l);
  }
}

// ---------------- K4: softmax finish + pa/attns writes + c_enc partial ----------------
// 1024 blocks = 64 b x 16 s-chunks of 64. atomicAdd into cenc (f32).
__global__ __launch_bounds__(256) void k_cenc(const float* __restrict__ ee,
                                              const float2* __restrict__ partials,
                                              const unsigned short* __restrict__ encb,
                                              float* __restrict__ attns_out,
                                              float* __restrict__ pa,
                                              float* __restrict__ cenc) {
  int b = blockIdx.x >> 4, chunk = blockIdx.x & 15;
  int tid = threadIdx.x, lane = tid & 63, wv = tid >> 6;
  __shared__ float red[8];
  __shared__ float attn_s[64];
  // combine the 256 per-block partials of batch b
  float2 p = partials[(b << 8) + tid];
  float m = p.x;
#pragma unroll
  for (int off = 32; off > 0; off >>= 1) m = fmaxf(m, __shfl_xor(m, off, 64));
  if (lane == 0) red[wv] = m;
  __syncthreads();
  float M = fmaxf(fmaxf(red[0], red[1]), fmaxf(red[2], red[3]));
  float lw = p.y * __expf(p.x - M);
#pragma unroll
  for (int off = 32; off > 0; off >>= 1) lw += __shfl_xor(lw, off, 64);
  if (lane == 0) red[4 + wv] = lw;
  __syncthreads();
  float invL = 1.f / (red[4] + red[5] + red[6] + red[7]);
  int s0 = chunk * 64;
  if (tid < 64) {
    float a = __expf(ee[(size_t)b * 1024 + s0 + tid] - M) * invL;
    attn_s[tid] = a;
    attns_out[(size_t)b * 1024 + s0 + tid] = a;
    pa[(size_t)b * 1024 + s0 + tid] += a;
  }
  __syncthreads();
  // stream encb rows s0..s0+63; thread owns cols 2*tid, 2*tid+1
  const uint32_t* epr = (const uint32_t*)(encb + ((size_t)b * 1024 + s0) * 512) + tid;
  float a0 = 0.f, a1 = 0.f;
#pragma unroll 8
  for (int si = 0; si < 64; ++si) {
    float w = attn_s[si];
    uint32_t pk = epr[(size_t)si * 256];
    a0 += w * bf2f((unsigned short)(pk & 0xffffu));
    a1 += w * bf2f((unsigned short)(pk >> 16));
  }
  atomicAdd(&cenc[(size_t)b * 512 + 2 * tid], a0);
  atomicAdd(&cenc[(size_t)b * 512 + 2 * tid + 1], a1);
}

// ---------------- K5: fused ha-GEMM + output writes + p_gen ----------------
__global__ __launch_bounds__(256) void k_ha_pout(
    const float* __restrict__ cenc, const unsigned short* __restrict__ hb,
    const unsigned short* __restrict__ Bm, const float* __restrict__ bias,
    float* __restrict__ ha,
    const float* __restrict__ input_, const float* __restrict__ h,
    const float* __restrict__ c,
    const float* __restrict__ wpt, const float* __restrict__ bpt,
    float* __restrict__ dout, int t) {
  if (blockIdx.x < 32) {
    int wid = (int)(blockIdx.x * 4 + (threadIdx.x >> 6));
    int lane = threadIdx.x & 63;
    int tm = wid & 3, tn = wid >> 2;
    int r = lane & 15, q = lane >> 4;
    int arow = tm * 16 + r;
    f32x4 acc = {0.f, 0.f, 0.f, 0.f};
#pragma unroll
    for (int kk = 0; kk < 32; ++kk) {
      int k0 = kk * 32 + q * 8;
      short8 a;
      if (k0 < 512) {
        const f32x4* p = (const f32x4*)(cenc + (size_t)arow * 512 + k0);
        a = pack_bf16x8(p[0], p[1]);
      } else {
        a = *(const short8*)(hb + (size_t)arow * 512 + (k0 - 512));
      }
      short8 bfr = *(const short8*)(Bm + (size_t)(tn * 16 + r) * 1024 + k0);
      acc = __builtin_amdgcn_mfma_f32_16x16x32_bf16(a, bfr, acc, 0, 0, 0);
    }
    int col = tn * 16 + r;
    float bv = bias[col];
#pragma unroll
    for (int rg = 0; rg < 4; ++rg) {
      int row = tm * 16 + q * 4 + rg;
      float v = acc[rg] + bv;
      ha[(size_t)row * 512 + col] = v;
      dout[((size_t)row * 100 + t) * 512 + col] = v;
      if (t == 99) dout[O_HAT + (size_t)row * 512 + col] = v;
    }
  } else {
    int b = blockIdx.x - 32, tid = threadIdx.x;
    float acc = 0.f;
#pragma unroll
    for (int k = tid; k < 1280; k += 256) {
      float x;
      if (k < 256)      x = input_[((size_t)b * 100 + t) * 256 + k];
      else if (k < 768) x = h[(size_t)b * 512 + (k - 256)];
      else              x = cenc[(size_t)b * 512 + (k - 768)];
      acc += x * wpt[k];
    }
    int wv = tid >> 6, lane = tid & 63;
    __shared__ float red[4];
#pragma unroll
    for (int off = 32; off > 0; off >>= 1) acc += __shfl_xor(acc, off, 64);
    if (lane == 0) red[wv] = acc;
    __syncthreads();
    if (tid == 0) {
      float p = fsigmoid(red[0] + red[1] + red[2] + red[3] + bpt[0]);
      dout[O_PGEN + (size_t)b * 100 + t] = p;
    }
    if (t == 99) {
      dout[O_HT + (size_t)b * 512 + tid]       = h[(size_t)b * 512 + tid];
      dout[O_HT + (size_t)b * 512 + 256 + tid] = h[(size_t)b * 512 + 256 + tid];
      dout[O_CT + (size_t)b * 512 + tid]       = c[(size_t)b * 512 + tid];
      dout[O_CT + (size_t)b * 512 + 256 + tid] = c[(size_t)b * 512 + 256 + tid];
    }
  }
}

extern "C" void kernel_launch(void* const* d_in, const int* in_sizes, int n_in,
                              void* d_out, int out_size, void* d_ws, size_t ws_size,
                              hipStream_t stream) {
  const float* input_    = (const float*)d_in[1];
  const float* h0        = (const float*)d_in[2];
  const float* c0        = (const float*)d_in[3];
  const float* h_attn    = (const float*)d_in[4];
  const float* encoder_hy= (const float*)d_in[5];
  const float* past_attn = (const float*)d_in[6];
  const float* past_dehy = (const float*)d_in[7];
  const float* w_ih      = (const float*)d_in[8];
  const float* b_ih      = (const float*)d_in[9];
  const float* w_hh      = (const float*)d_in[10];
  const float* b_hh      = (const float*)d_in[11];
  const float* w_en      = (const float*)d_in[12];
  const float* b_en      = (const float*)d_in[13];
  const float* w_de      = (const float*)d_in[14];
  const float* w_cv      = (const float*)d_in[15];
  const float* w_warp    = (const float*)d_in[16];
  const float* w_ao      = (const float*)d_in[17];
  const float* b_ao      = (const float*)d_in[18];
  const float* w_pt      = (const float*)d_in[19];
  const float* b_pt      = (const float*)d_in[20];

  char* ws = (char*)d_ws;
  unsigned short* encb  = (unsigned short*)(ws + 0);           //  67,108,864
  unsigned short* epb   = (unsigned short*)(ws + 67108864);    //  67,108,864
  unsigned short* wcomb = (unsigned short*)(ws + 134217728);   //   5,242,880
  unsigned short* wenb  = (unsigned short*)(ws + 139460608);   //     524,288
  unsigned short* wdeb  = (unsigned short*)(ws + 139984896);   //     524,288
  unsigned short* waob  = (unsigned short*)(ws + 140509184);   //   1,048,576
  float* biasc          = (float*)(ws + 141557760);            //       8,192
  float* h              = (float*)(ws + 141565952);            //     131,072
  float* c              = (float*)(ws + 141697024);            //     131,072
  float* ha             = (float*)(ws + 141828096);            //     131,072
  unsigned short* hbA   = (unsigned short*)(ws + 141959168);   //      65,536
  unsigned short* hbB   = (unsigned short*)(ws + 142024704);   //      65,536
  float* de             = (float*)(ws + 142090240);            //     131,072
  float* ee             = (float*)(ws + 142221312);            //     262,144
  float2* partials      = (float2*)(ws + 142483456);           //     131,072
  float* cenc           = (float*)(ws + 142614528);            //     131,072

  float* out = (float*)d_out;
  float* pa = out + O_PAT;  // pa state lives in the paT output slot

  // ---- init state ----
  hipMemcpyAsync(h,  h0,     32768 * 4, hipMemcpyDeviceToDevice, stream);
  hipMemcpyAsync(c,  c0,     32768 * 4, hipMemcpyDeviceToDevice, stream);
  hipMemcpyAsync(ha, h_attn, 32768 * 4, hipMemcpyDeviceToDevice, stream);
  hipMemcpyAsync(pa, past_attn, 65536 * 4, hipMemcpyDeviceToDevice, stream);
  hipMemcpyAsync(out + O_PDEHY, past_dehy, 32768 * 4, hipMemcpyDeviceToDevice, stream);
  hipMemsetAsync(out + O_LOSS, 0, 4, stream);

  // ---- one-time conversions + enc_proj ----
  k_conv_bf16<<<32768, 256, 0, stream>>>(encoder_hy, encb);
  k_conv_bf16<<<256, 256, 0, stream>>>(w_en, wenb);
  k_conv_bf16<<<256, 256, 0, stream>>>(w_de, wdeb);
  k_conv_bf16<<<512, 256, 0, stream>>>(w_ao, waob);
  k_conv_bf16<<<32, 256, 0, stream>>>(h0, hbA);
  k_build_wcomb<<<2560, 256, 0, stream>>>(w_ih, w_hh, wcomb);
  k_bias<<<8, 256, 0, stream>>>(b_ih, b_hh, biasc);

  // enc_proj (65536x512, K=512) -> bf16
  k_gemm_bt<4096, 32, 512, 1><<<32768, 256, 0, stream>>>(encb, wenb, b_en, epb, 512);

  for (int t = 0; t < 100; ++t) {
    unsigned short* hbp = (t & 1) ? hbB : hbA;
    unsigned short* hbn = (t & 1) ? hbA : hbB;
    k_gates_lstm<<<32, 256, 0, stream>>>(input_, ha, hbp, wcomb, biasc, h, c, hbn, cenc, t);
    k_gemm_bt<4, 32, 512, 0><<<32, 256, 0, stream>>>(hbn, wdeb, nullptr, de, 512);
    k_attn_ee<<<16384, 256, 0, stream>>>(epb, de, w_cv, w_warp, pa, ee, partials);
    k_cenc<<<1024, 256, 0, stream>>>(ee, partials, encb,
                                     out + O_ATTNS + (size_t)t * 65536, pa, cenc);
    k_ha_pout<<<96, 256, 0, stream>>>(cenc, hbn, waob, b_ao, ha,
                                      input_, h, c, w_pt, b_pt, out, t);
  }
}